// Round 1
// baseline (128.865 us; speedup 1.0000x reference)
//
#include <hip/hip_runtime.h>

// Single-level deformable attention.
// value: (bs, K=2500, H=8, D=32) f32
// value_spatial_shapes: (1,2) i64  (ignored; hardcoded 50x50)
// sampling_locations: (bs, Q=2000, H=8, L=1, P=4, 2) f32
// attention_weights:  (bs, Q, H, 1, P) f32
// out: (bs, Q, H*D=256) f32

#define FH 50
#define FW 50
#define KK (FH * FW)
#define NH 8
#define ND 32
#define NQ 2000
#define NP 4

__global__ __launch_bounds__(256) void deform_attn_kernel(
    const float* __restrict__ value,
    const float* __restrict__ loc,
    const float* __restrict__ attw,
    float* __restrict__ out)
{
    // One 32-lane group per (b,q,h); lane = channel d.
    const int g = blockIdx.x * 8 + (threadIdx.x >> 5);   // (b*Q + q)*H + h
    const int d = threadIdx.x & 31;
    const int h = g & (NH - 1);
    const int bq = g >> 3;            // b*Q + q
    const int b = bq / NQ;

    // value[b][k][h][d] with k varying: stride NH*ND floats between k's
    const float* __restrict__ vbase =
        value + ((size_t)b * KK * NH + (size_t)h) * ND + d;
    const float2* __restrict__ locp = (const float2*)(loc + (size_t)g * (NP * 2));
    const float* __restrict__ awp = attw + (size_t)g * NP;

    float acc = 0.f;
#pragma unroll
    for (int p = 0; p < NP; ++p) {
        const float2 l = locp[p];
        const float aw = awp[p];
        // grid = 2*loc-1; x = (grid+1)*w/2 - 0.5 = loc*w - 0.5
        const float x = l.x * (float)FW - 0.5f;
        const float y = l.y * (float)FH - 0.5f;
        const float x0f = floorf(x);
        const float y0f = floorf(y);
        const int x0 = (int)x0f, y0 = (int)y0f;
        const int x1 = x0 + 1, y1 = y0 + 1;
        const float wx1 = x - x0f, wx0 = 1.f - wx1;
        const float wy1 = y - y0f, wy0 = 1.f - wy1;

        const bool vx0 = (x0 >= 0) && (x0 < FW);
        const bool vx1 = (x1 >= 0) && (x1 < FW);
        const bool vy0 = (y0 >= 0) && (y0 < FH);
        const bool vy1 = (y1 >= 0) && (y1 < FH);

        const int cx0 = min(max(x0, 0), FW - 1);
        const int cx1 = min(max(x1, 0), FW - 1);
        const int cy0 = min(max(y0, 0), FH - 1);
        const int cy1 = min(max(y1, 0), FH - 1);

        // Always load clamped-in-bounds corners; zero out weight if OOB
        // (zeros padding_mode). Avoids divergent loads.
        const float v00 = vbase[(size_t)(cy0 * FW + cx0) * (NH * ND)];
        const float v10 = vbase[(size_t)(cy0 * FW + cx1) * (NH * ND)];
        const float v01 = vbase[(size_t)(cy1 * FW + cx0) * (NH * ND)];
        const float v11 = vbase[(size_t)(cy1 * FW + cx1) * (NH * ND)];

        float s = 0.f;
        s += ((vx0 && vy0) ? (wx0 * wy0) : 0.f) * v00;
        s += ((vx1 && vy0) ? (wx1 * wy0) : 0.f) * v10;
        s += ((vx0 && vy1) ? (wx0 * wy1) : 0.f) * v01;
        s += ((vx1 && vy1) ? (wx1 * wy1) : 0.f) * v11;
        acc += aw * s;
    }

    // out[b][q][h*ND + d]: block writes 256 contiguous floats (one bq row)
    out[(size_t)bq * (NH * ND) + h * ND + d] = acc;
}

extern "C" void kernel_launch(void* const* d_in, const int* in_sizes, int n_in,
                              void* d_out, int out_size, void* d_ws, size_t ws_size,
                              hipStream_t stream) {
    const float* value = (const float*)d_in[0];
    // d_in[1] = value_spatial_shapes (int64), ignored: hardcoded 50x50
    const float* loc  = (const float*)d_in[2];
    const float* attw = (const float*)d_in[3];
    float* out = (float*)d_out;

    const int bs = in_sizes[0] / (KK * NH * ND);       // 16
    const int groups = bs * NQ * NH;                   // 256000
    const int blocks = groups / 8;                     // 32000 blocks of 256

    deform_attn_kernel<<<blocks, 256, 0, stream>>>(value, loc, attw, out);
}

// Round 2
// 125.983 us; speedup vs baseline: 1.0229x; 1.0229x over previous
//
#include <hip/hip_runtime.h>

// Single-level deformable attention.
// value: (bs, K=2500, H=8, D=32) f32
// value_spatial_shapes: (1,2) i64  (ignored; hardcoded 50x50)
// sampling_locations: (bs, Q=2000, H=8, L=1, P=4, 2) f32
// attention_weights:  (bs, Q, H, 1, P) f32
// out: (bs, Q, H*D=256) f32
//
// R1: 32-lane group per (b,q,h), 1 float/lane -> 49.7us, VALUBusy 75%, HBM 42%.
//     VALU-bound: addressing replicated 32x per group.
// R2: 8-lane group per (b,q,h), each lane owns 4 channels (float4).
//     Address math amortized 4x, dwordx4 loads 4x fewer VMEM insts.

#define FH 50
#define FW 50
#define KK (FH * FW)
#define NH 8
#define ND 32
#define NQ 2000
#define NP 4

__global__ __launch_bounds__(256) void deform_attn_kernel(
    const float* __restrict__ value,
    const float* __restrict__ loc,
    const float* __restrict__ attw,
    float* __restrict__ out)
{
    // One 8-lane group per (b,q,h); lane = channel quad c (channels 4c..4c+3).
    const int gid = blockIdx.x * 32 + (threadIdx.x >> 3);  // (b*Q + q)*H + h
    const int c = threadIdx.x & 7;
    const int h = gid & (NH - 1);
    const int bq = gid >> 3;          // b*Q + q
    const int b = bq / NQ;

    // value[b][k][h][4c..4c+3]; stride between k's = NH*ND/4 = 64 float4
    const float4* __restrict__ vbase =
        (const float4*)value + ((size_t)b * KK * NH + (size_t)h) * (ND / 4) + c;

    // coords: 4 points x (x,y) = 32 B = two float4
    const float4* __restrict__ locp = (const float4*)loc + (size_t)gid * 2;
    const float4 lv0 = locp[0];
    const float4 lv1 = locp[1];
    const float4 aw4 = ((const float4*)attw)[gid];

    const float px[NP] = {lv0.x, lv0.z, lv1.x, lv1.z};
    const float py[NP] = {lv0.y, lv0.w, lv1.y, lv1.w};
    const float aw[NP] = {aw4.x, aw4.y, aw4.z, aw4.w};

    float4 acc = {0.f, 0.f, 0.f, 0.f};
#pragma unroll
    for (int p = 0; p < NP; ++p) {
        // grid = 2*loc-1; x = (grid+1)*w/2 - 0.5 = loc*w - 0.5
        const float x = px[p] * (float)FW - 0.5f;
        const float y = py[p] * (float)FH - 0.5f;
        const float x0f = floorf(x);
        const float y0f = floorf(y);
        const int x0 = (int)x0f, y0 = (int)y0f;
        const int x1 = x0 + 1, y1 = y0 + 1;
        const float wx1 = x - x0f, wx0 = 1.f - wx1;
        const float wy1 = y - y0f, wy0 = 1.f - wy1;

        const bool vx0 = (x0 >= 0) && (x0 < FW);
        const bool vx1 = (x1 >= 0) && (x1 < FW);
        const bool vy0 = (y0 >= 0) && (y0 < FH);
        const bool vy1 = (y1 >= 0) && (y1 < FH);

        const int cx0 = min(max(x0, 0), FW - 1);
        const int cx1 = min(max(x1, 0), FW - 1);
        const int cy0 = min(max(y0, 0), FH - 1);
        const int cy1 = min(max(y1, 0), FH - 1);

        // Clamped loads; zero weight if OOB (zeros padding_mode).
        const float4 v00 = vbase[(size_t)(cy0 * FW + cx0) * (NH * ND / 4)];
        const float4 v10 = vbase[(size_t)(cy0 * FW + cx1) * (NH * ND / 4)];
        const float4 v01 = vbase[(size_t)(cy1 * FW + cx0) * (NH * ND / 4)];
        const float4 v11 = vbase[(size_t)(cy1 * FW + cx1) * (NH * ND / 4)];

        const float w00 = ((vx0 && vy0) ? (wx0 * wy0) : 0.f) * aw[p];
        const float w10 = ((vx1 && vy0) ? (wx1 * wy0) : 0.f) * aw[p];
        const float w01 = ((vx0 && vy1) ? (wx0 * wy1) : 0.f) * aw[p];
        const float w11 = ((vx1 && vy1) ? (wx1 * wy1) : 0.f) * aw[p];

        acc.x += w00 * v00.x + w10 * v10.x + w01 * v01.x + w11 * v11.x;
        acc.y += w00 * v00.y + w10 * v10.y + w01 * v01.y + w11 * v11.y;
        acc.z += w00 * v00.z + w10 * v10.z + w01 * v01.z + w11 * v11.z;
        acc.w += w00 * v00.w + w10 * v10.w + w01 * v01.w + w11 * v11.w;
    }

    // out[b][q][h*32 + 4c .. +3]: block writes 4 KB contiguous (4 bq rows)
    ((float4*)out)[(size_t)bq * (NH * ND / 4) + h * (ND / 4) + c] = acc;
}

extern "C" void kernel_launch(void* const* d_in, const int* in_sizes, int n_in,
                              void* d_out, int out_size, void* d_ws, size_t ws_size,
                              hipStream_t stream) {
    const float* value = (const float*)d_in[0];
    // d_in[1] = value_spatial_shapes (int64), ignored: hardcoded 50x50
    const float* loc  = (const float*)d_in[2];
    const float* attw = (const float*)d_in[3];
    float* out = (float*)d_out;

    const int bs = in_sizes[0] / (KK * NH * ND);       // 16
    const int groups = bs * NQ * NH;                   // 256000
    const int blocks = groups / 32;                    // 8000 blocks of 256

    deform_attn_kernel<<<blocks, 256, 0, stream>>>(value, loc, attw, out);
}

// Round 3
// 119.373 us; speedup vs baseline: 1.0795x; 1.0554x over previous
//
#include <hip/hip_runtime.h>

// Single-level deformable attention.
// value: (bs=16, K=2500, H=8, D=32) f32
// sampling_locations: (bs, Q=2000, H=8, L=1, P=4, 2) f32
// attention_weights:  (bs, Q, H, 1, P) f32
// out: (bs, Q, H*D=256) f32
//
// R1: 32-lane/(b,q,h) scalar -> 49.7us, VALU-bound (75%).
// R2: 8-lane/(b,q,h) float4  -> 46us, VALU 24%, HBM 46%, occ 52%:
//     latency/L2-miss bound. Gather traffic ~524 MB vs 4 MB L2/XCD holding
//     random slices of all 16 batches (41 MB).
// R3: XCD-aware swizzle: batch b pinned to XCD (b%8) [hw maps blockIdx round-
//     robin over 8 XCDs], two phases (b<8 then b>=8). Per-XCD concurrent
//     working set = one 2.56 MB batch image -> L2-resident gather.

#define FH 50
#define FW 50
#define KK (FH * FW)
#define NH 8
#define ND 32
#define NQ 2000
#define NP 4

#define QPB 4                 // queries per block (32 groups of 8 lanes)
#define BLOCKS_PER_B (NQ / QPB)   // 500

__global__ __launch_bounds__(256) void deform_attn_kernel(
    const float* __restrict__ value,
    const float* __restrict__ loc,
    const float* __restrict__ attw,
    float* __restrict__ out)
{
    // ---- XCD-aware remap: blockIdx.x -> (b, q0) with b pinned to xcd ----
    const int x = blockIdx.x;
    const int xcd = x & 7;            // hw: round-robin blockIdx -> XCD
    const int slot = x >> 3;          // 0..999
    const int phase = (slot >= BLOCKS_PER_B) ? 1 : 0;
    const int b = xcd + (phase << 3);                 // batch pinned to xcd
    const int q0 = (slot - phase * BLOCKS_PER_B) * QPB;

    // One 8-lane group per (q,h); lane = channel quad c (channels 4c..4c+3).
    const int lg = threadIdx.x >> 3;       // 0..31 = local (q offset)*8 + h
    const int c = threadIdx.x & 7;
    const int h = lg & (NH - 1);
    const int q = q0 + (lg >> 3);
    const int bq = b * NQ + q;
    const int gid = bq * NH + h;

    // value[b][k][h][4c..4c+3]; stride between k's = NH*ND/4 = 64 float4
    const float4* __restrict__ vbase =
        (const float4*)value + ((size_t)b * KK * NH + (size_t)h) * (ND / 4) + c;

    // coords: 4 points x (x,y) = 32 B = two float4
    const float4* __restrict__ locp = (const float4*)loc + (size_t)gid * 2;
    const float4 lv0 = locp[0];
    const float4 lv1 = locp[1];
    const float4 aw4 = ((const float4*)attw)[gid];

    const float px[NP] = {lv0.x, lv0.z, lv1.x, lv1.z};
    const float py[NP] = {lv0.y, lv0.w, lv1.y, lv1.w};
    const float aw[NP] = {aw4.x, aw4.y, aw4.z, aw4.w};

    float4 acc = {0.f, 0.f, 0.f, 0.f};
#pragma unroll
    for (int p = 0; p < NP; ++p) {
        // grid = 2*loc-1; x = (grid+1)*w/2 - 0.5 = loc*w - 0.5
        const float fx = px[p] * (float)FW - 0.5f;
        const float fy = py[p] * (float)FH - 0.5f;
        const float x0f = floorf(fx);
        const float y0f = floorf(fy);
        const int x0 = (int)x0f, y0 = (int)y0f;
        const int x1 = x0 + 1, y1 = y0 + 1;
        const float wx1 = fx - x0f, wx0 = 1.f - wx1;
        const float wy1 = fy - y0f, wy0 = 1.f - wy1;

        const bool vx0 = (x0 >= 0) && (x0 < FW);
        const bool vx1 = (x1 >= 0) && (x1 < FW);
        const bool vy0 = (y0 >= 0) && (y0 < FH);
        const bool vy1 = (y1 >= 0) && (y1 < FH);

        const int cx0 = min(max(x0, 0), FW - 1);
        const int cx1 = min(max(x1, 0), FW - 1);
        const int cy0 = min(max(y0, 0), FH - 1);
        const int cy1 = min(max(y1, 0), FH - 1);

        // Clamped loads; zero weight if OOB (zeros padding_mode).
        const float4 v00 = vbase[(size_t)(cy0 * FW + cx0) * (NH * ND / 4)];
        const float4 v10 = vbase[(size_t)(cy0 * FW + cx1) * (NH * ND / 4)];
        const float4 v01 = vbase[(size_t)(cy1 * FW + cx0) * (NH * ND / 4)];
        const float4 v11 = vbase[(size_t)(cy1 * FW + cx1) * (NH * ND / 4)];

        const float w00 = ((vx0 && vy0) ? (wx0 * wy0) : 0.f) * aw[p];
        const float w10 = ((vx1 && vy0) ? (wx1 * wy0) : 0.f) * aw[p];
        const float w01 = ((vx0 && vy1) ? (wx0 * wy1) : 0.f) * aw[p];
        const float w11 = ((vx1 && vy1) ? (wx1 * wy1) : 0.f) * aw[p];

        acc.x += w00 * v00.x + w10 * v10.x + w01 * v01.x + w11 * v11.x;
        acc.y += w00 * v00.y + w10 * v10.y + w01 * v01.y + w11 * v11.y;
        acc.z += w00 * v00.z + w10 * v10.z + w01 * v01.z + w11 * v11.z;
        acc.w += w00 * v00.w + w10 * v10.w + w01 * v01.w + w11 * v11.w;
    }

    // out[b][q][h*32 + 4c .. +3]: block writes 4 KB contiguous (4 q rows)
    ((float4*)out)[(size_t)bq * (NH * ND / 4) + h * (ND / 4) + c] = acc;
}

extern "C" void kernel_launch(void* const* d_in, const int* in_sizes, int n_in,
                              void* d_out, int out_size, void* d_ws, size_t ws_size,
                              hipStream_t stream) {
    const float* value = (const float*)d_in[0];
    // d_in[1] = value_spatial_shapes (int64), ignored: hardcoded 50x50
    const float* loc  = (const float*)d_in[2];
    const float* attw = (const float*)d_in[3];
    float* out = (float*)d_out;

    const int blocks = 16 * BLOCKS_PER_B;   // 8000 blocks of 256
    deform_attn_kernel<<<blocks, 256, 0, stream>>>(value, loc, attw, out);
}

// Round 4
// 118.313 us; speedup vs baseline: 1.0892x; 1.0090x over previous
//
#include <hip/hip_runtime.h>

// Single-level deformable attention.
// value: (bs=16, K=2500, H=8, D=32) f32
// sampling_locations: (bs, Q=2000, H=8, L=1, P=4, 2) f32
// attention_weights:  (bs, Q, H, 1, P) f32
// out: (bs, Q, H*D=256) f32
//
// R1: 32-lane/(b,q,h) scalar -> 49.7us, VALU-bound (75%).
// R2: 8-lane/(b,q,h) float4  -> 46us, VALU 24%, HBM 46%: latency-bound.
// R3: XCD swizzle (batch pinned to XCD): FETCH 138->27MB but dur 42us.
//     VGPR=40 => compiler serialized the 16 gathers (MLP~3). Latency-bound.
// R4: MLP attack: launch_bounds(256,2) (VGPR cap 128), 2 queries/thread
//     (32 independent gathers), SGPR-base + 32-bit voffset addressing,
//     offsets/weights precomputed before the gather block.

#define FH 50
#define FW 50
#define KK (FH * FW)
#define NH 8
#define ND 32
#define NQ 2000
#define NP 4

#define QPB 8                     // queries per block; thread owns 2
#define BLOCKS_PER_B (NQ / QPB)   // 250

__global__ __launch_bounds__(256, 2) void deform_attn_kernel(
    const float* __restrict__ value,
    const float* __restrict__ loc,
    const float* __restrict__ attw,
    float* __restrict__ out)
{
    // ---- XCD-aware remap: batch b pinned to XCD (b&7) ----
    const int x = blockIdx.x;
    const int xcd = x & 7;            // hw: round-robin blockIdx -> XCD
    const int slot = x >> 3;          // 0..499
    const int phase = (slot >= BLOCKS_PER_B) ? 1 : 0;
    const int b = xcd + (phase << 3);
    const int q0 = (slot - phase * BLOCKS_PER_B) * QPB;

    const int t = threadIdx.x;
    const int c = t & 7;              // channel quad
    const int lg = t >> 3;            // 0..31
    const int h = lg & 7;
    const int qo = lg >> 3;           // 0..3; thread handles q0+qo and q0+qo+4

    // Uniform (per-block) byte base for this batch; per-lane 32-bit voffset.
    const char* __restrict__ vb =
        (const char*)(value + (size_t)b * KK * NH * ND);
    const int hc = h * (ND * 4) + c * 16;   // bytes within a k-row

    const int qA = q0 + qo;
    const int gidA = (b * NQ + qA) * NH + h;

    float4 accA = {0.f, 0.f, 0.f, 0.f};
    float4 accB = {0.f, 0.f, 0.f, 0.f};

    auto sample = [&](int gid, float4& acc) {
        const float4* __restrict__ lp = (const float4*)loc + (size_t)gid * 2;
        const float4 l0 = lp[0];
        const float4 l1 = lp[1];
        const float4 a4 = ((const float4*)attw)[gid];

        const float pxx[NP] = {l0.x, l0.z, l1.x, l1.z};
        const float pyy[NP] = {l0.y, l0.w, l1.y, l1.w};
        const float awp[NP] = {a4.x, a4.y, a4.z, a4.w};

        unsigned offs[16];
        float wts[16];
#pragma unroll
        for (int p = 0; p < NP; ++p) {
            const float fx = pxx[p] * (float)FW - 0.5f;
            const float fy = pyy[p] * (float)FH - 0.5f;
            const float x0f = floorf(fx);
            const float y0f = floorf(fy);
            const int x0 = (int)x0f, y0 = (int)y0f;
            const int x1 = x0 + 1, y1 = y0 + 1;
            const float wx1 = fx - x0f, wx0 = 1.f - wx1;
            const float wy1 = fy - y0f, wy0 = 1.f - wy1;

            const bool vx0 = (x0 >= 0) & (x0 < FW);
            const bool vx1 = (x1 >= 0) & (x1 < FW);
            const bool vy0 = (y0 >= 0) & (y0 < FH);
            const bool vy1 = (y1 >= 0) & (y1 < FH);

            const int cx0 = min(max(x0, 0), FW - 1);
            const int cx1 = min(max(x1, 0), FW - 1);
            const int cy0 = min(max(y0, 0), FH - 1);
            const int cy1 = min(max(y1, 0), FH - 1);

            // byte offset: k*1024 + h*128 + c*16
            offs[p * 4 + 0] = (unsigned)((cy0 * FW + cx0) * 1024 + hc);
            offs[p * 4 + 1] = (unsigned)((cy0 * FW + cx1) * 1024 + hc);
            offs[p * 4 + 2] = (unsigned)((cy1 * FW + cx0) * 1024 + hc);
            offs[p * 4 + 3] = (unsigned)((cy1 * FW + cx1) * 1024 + hc);

            wts[p * 4 + 0] = ((vx0 & vy0) ? (wx0 * wy0) : 0.f) * awp[p];
            wts[p * 4 + 1] = ((vx1 & vy0) ? (wx1 * wy0) : 0.f) * awp[p];
            wts[p * 4 + 2] = ((vx0 & vy1) ? (wx0 * wy1) : 0.f) * awp[p];
            wts[p * 4 + 3] = ((vx1 & vy1) ? (wx1 * wy1) : 0.f) * awp[p];
        }

        float4 v[16];
#pragma unroll
        for (int i = 0; i < 16; ++i)
            v[i] = *(const float4*)(vb + offs[i]);
#pragma unroll
        for (int i = 0; i < 16; ++i) {
            acc.x += wts[i] * v[i].x;
            acc.y += wts[i] * v[i].y;
            acc.z += wts[i] * v[i].z;
            acc.w += wts[i] * v[i].w;
        }
    };

    sample(gidA, accA);
    sample(gidA + 4 * NH, accB);

    // out rows: wave writes 1 KB contiguous per store
    float4* __restrict__ op = (float4*)out;
    op[(size_t)(b * NQ + qA) * (NH * ND / 4) + h * (ND / 4) + c] = accA;
    op[(size_t)(b * NQ + qA + 4) * (NH * ND / 4) + h * (ND / 4) + c] = accB;
}

extern "C" void kernel_launch(void* const* d_in, const int* in_sizes, int n_in,
                              void* d_out, int out_size, void* d_ws, size_t ws_size,
                              hipStream_t stream) {
    const float* value = (const float*)d_in[0];
    // d_in[1] = value_spatial_shapes (int64), ignored: hardcoded 50x50
    const float* loc  = (const float*)d_in[2];
    const float* attw = (const float*)d_in[3];
    float* out = (float*)d_out;

    const int blocks = 16 * BLOCKS_PER_B;   // 4000 blocks of 256
    deform_attn_kernel<<<blocks, 256, 0, stream>>>(value, loc, attw, out);
}